// Round 1
// baseline (1788.044 us; speedup 1.0000x reference)
//
#include <hip/hip_runtime.h>

#define T_LEN 2500
#define B_SZ  128
#define I_SZ  76
#define HID   32
#define G3    96   // 3*HID

// ---------------------------------------------------------------------------
// Kernel 1: xg[dir][b][t][g] = dot(X[b,t,:], W_ih[dir][g,:]) + b_ih[dir][g]
// grid: 1250 blocks x 256 threads, thread = (b,t)
// ---------------------------------------------------------------------------
__global__ __launch_bounds__(256) void xg_kernel(
    const float* __restrict__ X,
    const float* __restrict__ Wf, const float* __restrict__ bf,
    const float* __restrict__ Wb, const float* __restrict__ bb,
    float* __restrict__ xg)
{
    __shared__ __align__(16) float w[2 * G3 * I_SZ + 2 * G3];
    for (int i = threadIdx.x; i < G3 * I_SZ; i += 256) {
        w[i]               = Wf[i];
        w[G3 * I_SZ + i]   = Wb[i];
    }
    for (int i = threadIdx.x; i < G3; i += 256) {
        w[2 * G3 * I_SZ + i]      = bf[i];
        w[2 * G3 * I_SZ + G3 + i] = bb[i];
    }
    __syncthreads();

    const int tid = blockIdx.x * 256 + threadIdx.x;   // 0..319999
    const int b   = tid / T_LEN;
    const int t   = tid - b * T_LEN;

    // load x row (76 floats = 19 float4, 304B stride is 16B aligned)
    float x[I_SZ];
    const float4* xr4 = (const float4*)(X + (size_t)b * T_LEN * I_SZ + (size_t)t * I_SZ);
    #pragma unroll
    for (int i = 0; i < I_SZ / 4; ++i) {
        float4 v = xr4[i];
        x[4*i+0] = v.x; x[4*i+1] = v.y; x[4*i+2] = v.z; x[4*i+3] = v.w;
    }

    #pragma unroll 1
    for (int dir = 0; dir < 2; ++dir) {
        const float4* wd = (const float4*)(w + dir * G3 * I_SZ);
        const float*  bd = w + 2 * G3 * I_SZ + dir * G3;
        float* out = xg + (((size_t)dir * B_SZ + b) * T_LEN + t) * G3;

        #pragma unroll 1
        for (int g0 = 0; g0 < G3; g0 += 4) {
            float a0 = bd[g0+0], a1 = bd[g0+1], a2 = bd[g0+2], a3 = bd[g0+3];
            #pragma unroll
            for (int i4 = 0; i4 < I_SZ / 4; ++i4) {
                float4 w0 = wd[(g0+0) * (I_SZ/4) + i4];
                float4 w1 = wd[(g0+1) * (I_SZ/4) + i4];
                float4 w2 = wd[(g0+2) * (I_SZ/4) + i4];
                float4 w3 = wd[(g0+3) * (I_SZ/4) + i4];
                a0 = fmaf(x[4*i4+0], w0.x, a0); a0 = fmaf(x[4*i4+1], w0.y, a0);
                a0 = fmaf(x[4*i4+2], w0.z, a0); a0 = fmaf(x[4*i4+3], w0.w, a0);
                a1 = fmaf(x[4*i4+0], w1.x, a1); a1 = fmaf(x[4*i4+1], w1.y, a1);
                a1 = fmaf(x[4*i4+2], w1.z, a1); a1 = fmaf(x[4*i4+3], w1.w, a1);
                a2 = fmaf(x[4*i4+0], w2.x, a2); a2 = fmaf(x[4*i4+1], w2.y, a2);
                a2 = fmaf(x[4*i4+2], w2.z, a2); a2 = fmaf(x[4*i4+3], w2.w, a2);
                a3 = fmaf(x[4*i4+0], w3.x, a3); a3 = fmaf(x[4*i4+1], w3.y, a3);
                a3 = fmaf(x[4*i4+2], w3.z, a3); a3 = fmaf(x[4*i4+3], w3.w, a3);
            }
            float4 o; o.x = a0; o.y = a1; o.z = a2; o.w = a3;
            *(float4*)(out + g0) = o;
        }
    }
}

// ---------------------------------------------------------------------------
// Kernel 2: the sequential GRU scan. One wave (64 threads) per (b,dir) pair.
// lane l: k = l&31 (hidden index), kh = l>>5 (K-half for split dot products)
// grid: 256 blocks x 64 threads
// ---------------------------------------------------------------------------
__global__ __launch_bounds__(64) void scan_kernel(
    const float* __restrict__ xg,
    const float* __restrict__ Whf, const float* __restrict__ bhf,
    const float* __restrict__ Whb, const float* __restrict__ bhb,
    float* __restrict__ out)
{
    __shared__ __align__(16) float hsh[HID];

    const int l  = threadIdx.x;
    const int k  = l & 31;
    const int kh = l >> 5;
    const int p  = blockIdx.x;       // pair index 0..255
    const int dir = p >> 7;
    const int b   = p & 127;

    const float* Wh = dir ? Whb : Whf;
    const float* bh = dir ? bhb : bhf;

    // per-lane W_hh fragments: rows {k, 32+k, 64+k}, cols [kh*16, kh*16+16)
    float wr[16], wz[16], wn[16];
    {
        const float4* q;
        q = (const float4*)(Wh + (0*HID + k) * HID + kh * 16);
        #pragma unroll
        for (int i = 0; i < 4; ++i) { float4 v = q[i];
            wr[4*i+0]=v.x; wr[4*i+1]=v.y; wr[4*i+2]=v.z; wr[4*i+3]=v.w; }
        q = (const float4*)(Wh + (1*HID + k) * HID + kh * 16);
        #pragma unroll
        for (int i = 0; i < 4; ++i) { float4 v = q[i];
            wz[4*i+0]=v.x; wz[4*i+1]=v.y; wz[4*i+2]=v.z; wz[4*i+3]=v.w; }
        q = (const float4*)(Wh + (2*HID + k) * HID + kh * 16);
        #pragma unroll
        for (int i = 0; i < 4; ++i) { float4 v = q[i];
            wn[4*i+0]=v.x; wn[4*i+1]=v.y; wn[4*i+2]=v.z; wn[4*i+3]=v.w; }
    }
    // half-bias trick: both K-halves contribute bias*0.5, the shfl-combine sums to 1x
    const float bhr = 0.5f * bh[k];
    const float bhz = 0.5f * bh[32 + k];
    const float bhn = 0.5f * bh[64 + k];

    // xg stream for this pair; backward walks t downward
    const float* xbase = xg + ((size_t)p * T_LEN + (dir ? (T_LEN - 1) : 0)) * G3;
    const int step = dir ? -G3 : G3;

    float hh[16];
    #pragma unroll
    for (int j = 0; j < 16; ++j) hh[j] = 0.f;
    float hk = 0.f;

    // 4-deep prefetch ring (statically indexed via unroll-4)
    float px[4], py[4], pz[4];
    #pragma unroll
    for (int d = 0; d < 4; ++d) {
        const float* q = xbase + (long)d * step;
        px[d] = q[k]; py[d] = q[32 + k]; pz[d] = q[64 + k];
    }

    #pragma unroll 4
    for (int t = 0; t < T_LEN; ++t) {
        const int slot = t & 3;
        const float xr = px[slot], xz = py[slot], xn = pz[slot];
        if (t + 4 < T_LEN) {
            const float* q = xbase + (long)(t + 4) * step;
            px[slot] = q[k]; py[slot] = q[32 + k]; pz[slot] = q[64 + k];
        }

        // partial dots over this lane's K-half
        float hr = bhr, hz = bhz, hn = bhn;
        #pragma unroll
        for (int j = 0; j < 16; ++j) {
            hr = fmaf(wr[j], hh[j], hr);
            hz = fmaf(wz[j], hh[j], hz);
            hn = fmaf(wn[j], hh[j], hn);
        }
        // combine K-halves (lane l <-> l^32); both halves end with full sums
        hr += __shfl_xor(hr, 32, 64);
        hz += __shfl_xor(hz, 32, 64);
        hn += __shfl_xor(hn, 32, 64);

        const float r = __builtin_amdgcn_rcpf(
            1.f + __builtin_amdgcn_exp2f(-1.442695040888963f * (xr + hr)));
        const float z = __builtin_amdgcn_rcpf(
            1.f + __builtin_amdgcn_exp2f(-1.442695040888963f * (xz + hz)));
        float a = xn + r * hn;
        a = fminf(15.f, fmaxf(-15.f, a));
        const float E = __builtin_amdgcn_exp2f(2.885390081777927f * a);
        const float n = (E - 1.f) * __builtin_amdgcn_rcpf(E + 1.f);
        hk = n + z * (hk - n);

        // broadcast h_new: lanes l and l+32 write identical values to hsh[k];
        // single-wave block => ordering via compiler-inserted lgkmcnt, no barrier
        hsh[k] = hk;
        const float4* hv = (const float4*)(hsh + kh * 16);
        float4 h0 = hv[0], h1 = hv[1], h2 = hv[2], h3 = hv[3];
        hh[ 0]=h0.x; hh[ 1]=h0.y; hh[ 2]=h0.z; hh[ 3]=h0.w;
        hh[ 4]=h1.x; hh[ 5]=h1.y; hh[ 6]=h1.z; hh[ 7]=h1.w;
        hh[ 8]=h2.x; hh[ 9]=h2.y; hh[10]=h2.z; hh[11]=h2.w;
        hh[12]=h3.x; hh[13]=h3.y; hh[14]=h3.z; hh[15]=h3.w;
    }

    // output: (B, 2, H)
    if (l < 32) out[(b * 2 + dir) * HID + k] = hk;
}

extern "C" void kernel_launch(void* const* d_in, const int* in_sizes, int n_in,
                              void* d_out, int out_size, void* d_ws, size_t ws_size,
                              hipStream_t stream) {
    const float* X    = (const float*)d_in[0];
    const float* Wihf = (const float*)d_in[1];
    const float* Whhf = (const float*)d_in[2];
    const float* bihf = (const float*)d_in[3];
    const float* bhhf = (const float*)d_in[4];
    const float* Wihb = (const float*)d_in[5];
    const float* Whhb = (const float*)d_in[6];
    const float* bihb = (const float*)d_in[7];
    const float* bhhb = (const float*)d_in[8];
    float* out = (float*)d_out;
    float* xg  = (float*)d_ws;

    const size_t needed = (size_t)2 * B_SZ * T_LEN * G3 * sizeof(float); // 245.76 MB
    if (ws_size < needed) return;  // visible-fail guard: learn ws_size from bench

    xg_kernel<<<(B_SZ * T_LEN) / 256, 256, 0, stream>>>(X, Wihf, bihf, Wihb, bihb, xg);
    scan_kernel<<<256, 64, 0, stream>>>(xg, Whhf, bhhf, Whhb, bhhb, out);
}